// Round 1
// baseline (202.242 us; speedup 1.0000x reference)
//
#include <hip/hip_runtime.h>

// ALayer: out = conv3x3(x, weight*A_w) * sigmoid(conv3x3(relu(conv3x3(x,se_w1)), se_w2))
// B=8, C=256, H=W=56. bf16 MFMA implicit GEMM on NHWC-padded input.

typedef unsigned short u16;
typedef __bf16 bf16x8 __attribute__((ext_vector_type(8)));
typedef unsigned short us8 __attribute__((ext_vector_type(8)));
typedef unsigned short us4v __attribute__((ext_vector_type(4)));
typedef float f32x4 __attribute__((ext_vector_type(4)));
typedef float f4v __attribute__((ext_vector_type(4)));

#define NB 8
#define NC 256
#define NH 56
#define NW 56
#define HP 58   // padded
#define HW 3136 // 56*56

__device__ __forceinline__ u16 f2bf(float f) {
  unsigned u = __float_as_uint(f);
  u = (u + 0x7fffu + ((u >> 16) & 1u)) >> 16;  // RNE, inputs finite
  return (u16)u;
}
__device__ __forceinline__ float bf2f(u16 v) {
  return __uint_as_float(((unsigned)v) << 16);
}

// ---------- prep: wb[tap][o][c] = bf16(weight[o][c][tap] * A_w[c][tap]);
//            w1b[tap][o16][c] = bf16(se_w1[o][c][tap])
__global__ void k_prep(const float* __restrict__ weight, const float* __restrict__ A_w,
                       const float* __restrict__ se_w1, u16* __restrict__ wb,
                       u16* __restrict__ w1b) {
  int idx = blockIdx.x * 256 + threadIdx.x;
  if (idx < 589824) {
    int tap = idx >> 16; int rem = idx & 65535; int o = rem >> 8; int c = rem & 255;
    wb[idx] = f2bf(weight[(o * 256 + c) * 9 + tap] * A_w[c * 9 + tap]);
  } else if (idx < 589824 + 36864) {
    int j = idx - 589824;
    int tap = j >> 12; int rem = j & 4095; int o = rem >> 8; int c = rem & 255;
    w1b[j] = f2bf(se_w1[(o * 256 + c) * 9 + tap]);
  }
}

// ---------- transform: x NCHW fp32 -> xp[b][58][58][256] bf16 (interior only; border pre-zeroed)
__global__ __launch_bounds__(256) void k_transform(const float* __restrict__ x,
                                                   u16* __restrict__ xp) {
  __shared__ __align__(16) u16 trans[56 * 72];
  const int t = threadIdx.x;
  const int h = blockIdx.x;
  const int b = blockIdx.y;
  for (int cc = 0; cc < 4; ++cc) {
    const int c0 = cc * 64;
    // phase 1: read x[b][c0+ci][h][s*4..s*4+3], write transposed to LDS
#pragma unroll
    for (int i = 0; i < 4; ++i) {
      int idx = t + 256 * i;
      if (idx < 896) {
        int ci = idx / 14, s = idx % 14;
        f4v v = *(const f4v*)(x + ((size_t)(b * 256 + c0 + ci)) * HW + h * 56 + s * 4);
#pragma unroll
        for (int j = 0; j < 4; ++j) trans[(s * 4 + j) * 72 + ci] = f2bf(v[j]);
      }
    }
    __syncthreads();
    // phase 2: write 16B chunks of [w][64ch] to global NHWC
#pragma unroll
    for (int i = 0; i < 2; ++i) {
      int idx = t + 256 * i;
      if (idx < 448) {
        int w = idx >> 3, seg = idx & 7;
        us8 v = *(const us8*)&trans[w * 72 + seg * 8];
        *(us8*)(xp + ((size_t)((b * HP + h + 1) * HP + (w + 1))) * 256 + c0 + seg * 8) = v;
      }
    }
    __syncthreads();
  }
}

// ---------- SE conv1: M=16, BN=128 (2 rows x 64), BK=64, 4 waves
__global__ __launch_bounds__(256) void k_se1(const u16* __restrict__ xp,
                                             const u16* __restrict__ w1b,
                                             u16* __restrict__ se1p) {
  __shared__ __align__(16) u16 Alds[16 * 72];
  __shared__ __align__(16) u16 Blds[2 * 64 * 72];
  const int t = threadIdx.x;
  const int lane = t & 63;
  const int wn = t >> 6;            // 0..3 -> n range 32
  const int l15 = lane & 15, lg = lane >> 4;
  const int h0 = blockIdx.x * 2;
  const int b = blockIdx.y;

  f32x4 acc[2];
  f32x4 z = {0.f, 0.f, 0.f, 0.f};
  acc[0] = z; acc[1] = z;

  for (int dh = 0; dh < 3; ++dh) {
    for (int dw = 0; dw < 3; ++dw) {
      const int tap = dh * 3 + dw;
      for (int cc = 0; cc < 4; ++cc) {
        const int c0 = cc * 64;
        __syncthreads();
        if (t < 128) {  // A: 16 rows x 8 chunks
          int row = t >> 3, seg = t & 7;
          us8 v = *(const us8*)(w1b + ((tap * 16 + row) * 256 + c0 + seg * 8));
          *(us8*)&Alds[row * 72 + seg * 8] = v;
        }
#pragma unroll
        for (int i = 0; i < 4; ++i) {  // B: 2 rows x 64 w x 8 chunks = 1024
          int idx = t + 256 * i;
          int r = idx >> 9, rem = idx & 511;
          int w = rem >> 3, seg = rem & 7;
          int col = w + dw;
          us8 v{};
          if (col < 58)
            v = *(const us8*)(xp + ((size_t)((b * HP + h0 + r + dh) * HP + col)) * 256 + c0 + seg * 8);
          *(us8*)&Blds[(r * 64 + w) * 72 + seg * 8] = v;
        }
        __syncthreads();
#pragma unroll
        for (int kk = 0; kk < 2; ++kk) {
          bf16x8 af = *(const bf16x8*)&Alds[l15 * 72 + kk * 32 + lg * 8];
#pragma unroll
          for (int nt = 0; nt < 2; ++nt) {
            int n = wn * 32 + nt * 16 + l15;
            int r = n >> 6, w = n & 63;
            bf16x8 bfrag = *(const bf16x8*)&Blds[(r * 64 + w) * 72 + kk * 32 + lg * 8];
            acc[nt] = __builtin_amdgcn_mfma_f32_16x16x32_bf16(af, bfrag, acc[nt], 0, 0, 0);
          }
        }
      }
    }
  }
  // epilogue: relu -> bf16, NHWC padded store
#pragma unroll
  for (int nt = 0; nt < 2; ++nt) {
    int n = wn * 32 + nt * 16 + l15;
    int r = n >> 6, w = n & 63;
    if (w < 56) {
      us4v pk;
#pragma unroll
      for (int reg = 0; reg < 4; ++reg) {
        float v = acc[nt][reg];
        v = v > 0.f ? v : 0.f;
        pk[reg] = f2bf(v);
      }
      *(us4v*)(se1p + ((size_t)((b * HP + h0 + r + 1) * HP + (w + 1))) * 16 + lg * 4) = pk;
    }
  }
}

// ---------- SE conv2 + sigmoid: direct, K=144
__global__ __launch_bounds__(256) void k_se2(const u16* __restrict__ se1p,
                                             const float* __restrict__ se_w2,
                                             float* __restrict__ amap) {
  __shared__ float w2[144];
  const int t = threadIdx.x;
  if (t < 144) w2[t] = se_w2[t];
  __syncthreads();
  int gid = blockIdx.x * 256 + t;
  int b = gid / HW, p = gid % HW, h = p / 56, w = p % 56;
  float s = 0.f;
  for (int dh = 0; dh < 3; ++dh) {
    for (int dw = 0; dw < 3; ++dw) {
      const u16* src = se1p + ((size_t)((b * HP + h + dh) * HP + (w + dw))) * 16;
      us8 v0 = *(const us8*)src;
      us8 v1 = *(const us8*)(src + 8);
#pragma unroll
      for (int ci = 0; ci < 8; ++ci) s += bf2f(v0[ci]) * w2[ci * 9 + dh * 3 + dw];
#pragma unroll
      for (int ci = 0; ci < 8; ++ci) s += bf2f(v1[ci]) * w2[(8 + ci) * 9 + dh * 3 + dw];
    }
  }
  amap[gid] = 1.f / (1.f + expf(-s));
}

// ---------- main conv: BM=128, BN=256 (4 rows x 64), BK=64, 8 waves (2x4)
__global__ __launch_bounds__(512) void k_main(const u16* __restrict__ xp,
                                              const u16* __restrict__ wb,
                                              const float* __restrict__ amap,
                                              float* __restrict__ out) {
  __shared__ __align__(16) u16 Alds[128 * 72];      // 18432 B
  __shared__ __align__(16) u16 Blds[4 * 64 * 72];   // 36864 B
  const int t = threadIdx.x;
  const int lane = t & 63;
  const int wid = t >> 6;
  const int wm = wid >> 2;          // 0..1 : 64 out-channels
  const int wn = wid & 3;           // 0..3 : 64 pixels (= 1 image row)
  const int l15 = lane & 15, lg = lane >> 4;
  const int mbase = blockIdx.x * 128;
  const int h0 = blockIdx.y * 4;
  const int b = blockIdx.z;

  f32x4 acc[4][4];
  f32x4 z = {0.f, 0.f, 0.f, 0.f};
#pragma unroll
  for (int mt = 0; mt < 4; ++mt)
#pragma unroll
    for (int nt = 0; nt < 4; ++nt) acc[mt][nt] = z;

  for (int dh = 0; dh < 3; ++dh) {
    for (int dw = 0; dw < 3; ++dw) {
      const int tap = dh * 3 + dw;
      for (int cc = 0; cc < 4; ++cc) {
        const int c0 = cc * 64;
        __syncthreads();
        // stage A: 128 rows x 8 x 16B = 1024 chunks
#pragma unroll
        for (int i = 0; i < 2; ++i) {
          int idx = t + 512 * i;
          int row = idx >> 3, seg = idx & 7;
          us8 v = *(const us8*)(wb + ((tap * 256 + mbase + row) * 256 + c0 + seg * 8));
          *(us8*)&Alds[row * 72 + seg * 8] = v;
        }
        // stage B: 4 rows x 64 w x 8 x 16B = 2048 chunks
#pragma unroll
        for (int i = 0; i < 4; ++i) {
          int idx = t + 512 * i;
          int r = idx >> 9, rem = idx & 511;
          int w = rem >> 3, seg = rem & 7;
          int col = w + dw;
          us8 v{};
          if (col < 58)
            v = *(const us8*)(xp + ((size_t)((b * HP + h0 + r + dh) * HP + col)) * 256 + c0 + seg * 8);
          *(us8*)&Blds[(r * 64 + w) * 72 + seg * 8] = v;
        }
        __syncthreads();
        // compute: 2 kk x 16 MFMA
#pragma unroll
        for (int kk = 0; kk < 2; ++kk) {
          bf16x8 af[4], bfr[4];
#pragma unroll
          for (int mt = 0; mt < 4; ++mt)
            af[mt] = *(const bf16x8*)&Alds[(wm * 64 + mt * 16 + l15) * 72 + kk * 32 + lg * 8];
#pragma unroll
          for (int nt = 0; nt < 4; ++nt) {
            int n = wn * 64 + nt * 16 + l15;  // r = wn, w = nt*16+l15
            bfr[nt] = *(const bf16x8*)&Blds[((n >> 6) * 64 + (n & 63)) * 72 + kk * 32 + lg * 8];
          }
#pragma unroll
          for (int mt = 0; mt < 4; ++mt)
#pragma unroll
            for (int nt = 0; nt < 4; ++nt)
              acc[mt][nt] = __builtin_amdgcn_mfma_f32_16x16x32_bf16(af[mt], bfr[nt], acc[mt][nt], 0, 0, 0);
        }
      }
    }
  }
  // epilogue: multiply by attention map, store NCHW fp32
#pragma unroll
  for (int nt = 0; nt < 4; ++nt) {
    int n = wn * 64 + nt * 16 + l15;
    int r = n >> 6, w = n & 63;
    if (w < 56) {
      float av = amap[(b * 56 + h0 + r) * 56 + w];
#pragma unroll
      for (int mt = 0; mt < 4; ++mt) {
        int obase = mbase + wm * 64 + mt * 16 + lg * 4;
#pragma unroll
        for (int reg = 0; reg < 4; ++reg) {
          out[((size_t)(b * 256 + obase + reg) * 56 + h0 + r) * 56 + w] = acc[mt][nt][reg] * av;
        }
      }
    }
  }
}

extern "C" void kernel_launch(void* const* d_in, const int* in_sizes, int n_in,
                              void* d_out, int out_size, void* d_ws, size_t ws_size,
                              hipStream_t stream) {
  const float* x      = (const float*)d_in[0];
  const float* weight = (const float*)d_in[1];
  const float* A_w    = (const float*)d_in[2];
  const float* se_w1  = (const float*)d_in[3];
  const float* se_w2  = (const float*)d_in[4];
  float* out = (float*)d_out;

  char* ws = (char*)d_ws;
  // layout (bytes):
  // xp   : [8][58][58][256] bf16 = 13,778,944
  // se1p : [8][58][58][16]  bf16 =    861,184   (both zero-padded -> memset)
  // wb   : [9][256][256]    bf16 =  1,179,648
  // w1b  : [9][16][256]     bf16 =     73,728
  // amap : [8][56][56]      f32  =    100,352
  u16* xp    = (u16*)ws;
  u16* se1p  = (u16*)(ws + 13778944);
  u16* wb    = (u16*)(ws + 14640128);
  u16* w1b   = (u16*)(ws + 15819776);
  float* amap = (float*)(ws + 15893504);

  hipMemsetAsync(ws, 0, 14640128, stream);  // zero xp + se1p (padding)
  k_prep<<<dim3((589824 + 36864 + 255) / 256), dim3(256), 0, stream>>>(weight, A_w, se_w1, wb, w1b);
  k_transform<<<dim3(56, 8), dim3(256), 0, stream>>>(x, xp);
  k_se1<<<dim3(28, 8), dim3(256), 0, stream>>>(xp, w1b, se1p);
  k_se2<<<dim3(98), dim3(256), 0, stream>>>(se1p, se_w2, amap);
  k_main<<<dim3(2, 14, 8), dim3(512), 0, stream>>>(xp, wb, amap, out);
}

// Round 2
// 172.692 us; speedup vs baseline: 1.1711x; 1.1711x over previous
//
#include <hip/hip_runtime.h>

// ALayer: out = conv3x3(x, weight*A_w) * sigmoid(conv3x3(relu(conv3x3(x,se_w1)), se_w2))
// B=8, C=256, H=W=56. bf16 MFMA implicit GEMM on NHWC-padded input.
// Round 2: global_load_lds(16B) + XOR-swizzled linear LDS in k_main (grid 448),
//          SE1 split over channel-blocks with fp32 atomic accumulation in d_out.

typedef unsigned short u16;
typedef __bf16 bf16x8 __attribute__((ext_vector_type(8)));
typedef unsigned short us8 __attribute__((ext_vector_type(8)));
typedef float f32x4 __attribute__((ext_vector_type(4)));
typedef float f4v __attribute__((ext_vector_type(4)));

#define HP 58   // padded H/W
#define HW 3136 // 56*56

__device__ __forceinline__ u16 f2bf(float f) {
  unsigned u = __float_as_uint(f);
  u = (u + 0x7fffu + ((u >> 16) & 1u)) >> 16;  // RNE, inputs finite
  return (u16)u;
}
__device__ __forceinline__ float bf2f(u16 v) {
  return __uint_as_float(((unsigned)v) << 16);
}

// async global->LDS, 16B per lane. LDS dest is wave-uniform base + lane*16.
__device__ __forceinline__ void gload16(const u16* g, u16* l) {
  __builtin_amdgcn_global_load_lds((const __attribute__((address_space(1))) void*)g,
                                   (__attribute__((address_space(3))) void*)l,
                                   16, 0, 0);
}

// ---------- prep: wb[tap][o][c] = bf16(weight[o][c][tap] * A_w[c][tap]);
//            w1b[tap][o16][c] = bf16(se_w1[o][c][tap])
__global__ void k_prep(const float* __restrict__ weight, const float* __restrict__ A_w,
                       const float* __restrict__ se_w1, u16* __restrict__ wb,
                       u16* __restrict__ w1b) {
  int idx = blockIdx.x * 256 + threadIdx.x;
  if (idx < 589824) {
    int tap = idx >> 16; int rem = idx & 65535; int o = rem >> 8; int c = rem & 255;
    wb[idx] = f2bf(weight[(o * 256 + c) * 9 + tap] * A_w[c * 9 + tap]);
  } else if (idx < 589824 + 36864) {
    int j = idx - 589824;
    int tap = j >> 12; int rem = j & 4095; int o = rem >> 8; int c = rem & 255;
    w1b[j] = f2bf(se_w1[(o * 256 + c) * 9 + tap]);
  }
}

// ---------- transform: x NCHW fp32 -> xp[b][58][58][256] bf16 (interior; border pre-zeroed)
__global__ __launch_bounds__(256) void k_transform(const float* __restrict__ x,
                                                   u16* __restrict__ xp) {
  __shared__ __align__(16) u16 trans[56 * 72];
  const int t = threadIdx.x;
  const int h = blockIdx.x;
  const int b = blockIdx.y;
  for (int cc = 0; cc < 4; ++cc) {
    const int c0 = cc * 64;
#pragma unroll
    for (int i = 0; i < 4; ++i) {
      int idx = t + 256 * i;
      if (idx < 896) {
        int ci = idx / 14, s = idx % 14;
        f4v v = *(const f4v*)(x + ((size_t)(b * 256 + c0 + ci)) * HW + h * 56 + s * 4);
#pragma unroll
        for (int j = 0; j < 4; ++j) trans[(s * 4 + j) * 72 + ci] = f2bf(v[j]);
      }
    }
    __syncthreads();
#pragma unroll
    for (int i = 0; i < 2; ++i) {
      int idx = t + 256 * i;
      if (idx < 448) {
        int w = idx >> 3, seg = idx & 7;
        us8 v = *(const us8*)&trans[w * 72 + seg * 8];
        *(us8*)(xp + ((size_t)((b * HP + h + 1) * HP + (w + 1))) * 256 + c0 + seg * 8) = v;
      }
    }
    __syncthreads();
  }
}

// ---------- SE conv1 (pre-relu): K split over 4 channel-blocks, atomic f32 accumulate.
// se1_pre[b][56][56][16] fp32 lives in d_out (zeroed by memset each call).
__global__ __launch_bounds__(256) void k_se1(const u16* __restrict__ xp,
                                             const u16* __restrict__ w1b,
                                             float* __restrict__ se1_pre) {
  __shared__ __align__(16) u16 Alds[144 * 72];  // 9 taps x 16 rows
  __shared__ __align__(16) u16 Blds[128 * 72];
  const int t = threadIdx.x;
  const int lane = t & 63;
  const int wv = t >> 6;  // 0..3
  const int l15 = lane & 15, lg = lane >> 4;
  const int h0 = blockIdx.x * 2;
  const int b = blockIdx.y;
  const int c0 = blockIdx.z * 64;

  // stage whole A once: 144 rows x 8 segs
  for (int idx = t; idx < 1152; idx += 256) {
    int row = idx >> 3, seg = idx & 7;
    us8 v = *(const us8*)(w1b + ((size_t)row * 256 + c0 + seg * 8));
    *(us8*)&Alds[row * 72 + seg * 8] = v;
  }

  f32x4 acc[2];
  f32x4 z = {0.f, 0.f, 0.f, 0.f};
  acc[0] = z; acc[1] = z;

  for (int dh = 0; dh < 3; ++dh) {
    for (int dw = 0; dw < 3; ++dw) {
      const int tap = dh * 3 + dw;
      __syncthreads();
#pragma unroll
      for (int i = 0; i < 4; ++i) {
        int idx = t + 256 * i;
        int p = idx >> 3, seg = idx & 7;
        int r = p >> 6, w = p & 63, col = w + dw;
        us8 v{};
        if (col < 58)
          v = *(const us8*)(xp + ((size_t)((b * HP + h0 + r + dh) * HP + col)) * 256 + c0 + seg * 8);
        *(us8*)&Blds[p * 72 + seg * 8] = v;
      }
      __syncthreads();
#pragma unroll
      for (int kk = 0; kk < 2; ++kk) {
        bf16x8 af = *(const bf16x8*)&Alds[(tap * 16 + l15) * 72 + kk * 32 + lg * 8];
#pragma unroll
        for (int nt = 0; nt < 2; ++nt) {
          int p = wv * 32 + nt * 16 + l15;
          bf16x8 bfrag = *(const bf16x8*)&Blds[p * 72 + kk * 32 + lg * 8];
          acc[nt] = __builtin_amdgcn_mfma_f32_16x16x32_bf16(af, bfrag, acc[nt], 0, 0, 0);
        }
      }
    }
  }
#pragma unroll
  for (int nt = 0; nt < 2; ++nt) {
    int p = wv * 32 + nt * 16 + l15;
    int r = p >> 6, w = p & 63;
    if (w < 56) {
      int base = ((b * 56 + h0 + r) * 56 + w) * 16 + lg * 4;
#pragma unroll
      for (int reg = 0; reg < 4; ++reg)
        atomicAdd(&se1_pre[base + reg], acc[nt][reg]);
    }
  }
}

// ---------- SE conv2 + relu + sigmoid: direct, K=144
__global__ __launch_bounds__(64) void k_se2(const float* __restrict__ se1_pre,
                                            const float* __restrict__ se_w2,
                                            float* __restrict__ amap) {
  __shared__ float w2s[144];
  const int t = threadIdx.x;
  for (int i = t; i < 144; i += 64) w2s[i] = se_w2[i];
  __syncthreads();
  int gid = blockIdx.x * 64 + t;
  int b = gid / HW, p = gid % HW, h = p / 56, w = p % 56;
  float s = 0.f;
  for (int dh = 0; dh < 3; ++dh) {
    int ih = h + dh - 1;
    if (ih < 0 || ih >= 56) continue;
    for (int dw = 0; dw < 3; ++dw) {
      int iw = w + dw - 1;
      if (iw < 0 || iw >= 56) continue;
      const float* src = se1_pre + ((size_t)((b * 56 + ih) * 56 + iw)) * 16;
      int tap = dh * 3 + dw;
#pragma unroll
      for (int c4 = 0; c4 < 4; ++c4) {
        f4v v = *(const f4v*)(src + c4 * 4);
#pragma unroll
        for (int j = 0; j < 4; ++j) {
          float vv = v[j] > 0.f ? v[j] : 0.f;
          s += vv * w2s[(c4 * 4 + j) * 9 + tap];
        }
      }
    }
  }
  amap[gid] = 1.f / (1.f + expf(-s));
}

// ---------- main conv: BM=128, BN=128 (2 rows x 64), 4 waves (2x2), gload_lds + swizzle
__global__ __launch_bounds__(256) void k_main(const u16* __restrict__ xp,
                                              const u16* __restrict__ wb,
                                              const float* __restrict__ amap,
                                              float* __restrict__ out) {
  __shared__ __align__(16) u16 Alds[128 * 64];  // 16 KB, linear [row][8 segs of 16B]
  __shared__ __align__(16) u16 Blds[128 * 64];  // 16 KB, linear [pixel][8 segs]
  const int t = threadIdx.x;
  const int lane = t & 63;
  const int wid = t >> 6;
  const int wm = wid >> 1;          // 0..1 : 64 out-channels
  const int wn = wid & 1;           // 0..1 : 64 pixels
  const int l15 = lane & 15, lg = lane >> 4;
  const int lrow = lane >> 3, lseg = lane & 7;
  const int mbase = blockIdx.x * 128;
  const int h0 = blockIdx.y * 2;
  const int b = blockIdx.z;

  f32x4 acc[4][4];
  f32x4 z = {0.f, 0.f, 0.f, 0.f};
#pragma unroll
  for (int mt = 0; mt < 4; ++mt)
#pragma unroll
    for (int nt = 0; nt < 4; ++nt) acc[mt][nt] = z;

  for (int dh = 0; dh < 3; ++dh) {
    for (int dw = 0; dw < 3; ++dw) {
      const int tap = dh * 3 + dw;
      for (int cc = 0; cc < 4; ++cc) {
        const int c0 = cc * 64;
        // stage: each wave issues 4 A-loads + 4 B-loads (1 KB each).
        // LDS linear; source pre-swizzled seg^=(row&7) so swizzled reads are conflict-free.
#pragma unroll
        for (int i = 0; i < 4; ++i) {
          int li = wid * 4 + i;
          int row = li * 8 + lrow;  // 0..127 (A-row / B-pixel)
          const u16* srcA = wb + ((size_t)(tap * 256 + mbase + row)) * 256 + c0 +
                            ((lseg ^ (row & 7)) * 8);
          gload16(srcA, &Alds[li * 512]);
          int r = row >> 6, w = row & 63;
          const u16* srcB = xp +
                            ((size_t)((b * HP + h0 + r + dh) * HP + (w + dw))) * 256 + c0 +
                            ((lseg ^ (row & 7)) * 8);
          gload16(srcB, &Blds[li * 512]);
        }
        __syncthreads();  // drains vmcnt -> tiles visible
#pragma unroll
        for (int kk = 0; kk < 2; ++kk) {
          bf16x8 af[4], bfr[4];
#pragma unroll
          for (int mt = 0; mt < 4; ++mt) {
            int row = wm * 64 + mt * 16 + l15;
            af[mt] = *(const bf16x8*)&Alds[row * 64 + (((kk * 4 + lg) ^ (row & 7)) * 8)];
          }
#pragma unroll
          for (int nt = 0; nt < 4; ++nt) {
            int p = wn * 64 + nt * 16 + l15;
            bfr[nt] = *(const bf16x8*)&Blds[p * 64 + (((kk * 4 + lg) ^ (p & 7)) * 8)];
          }
#pragma unroll
          for (int mt = 0; mt < 4; ++mt)
#pragma unroll
            for (int nt = 0; nt < 4; ++nt)
              acc[mt][nt] = __builtin_amdgcn_mfma_f32_16x16x32_bf16(af[mt], bfr[nt], acc[mt][nt], 0, 0, 0);
        }
        __syncthreads();  // compute done before next stage overwrites
      }
    }
  }
  // epilogue: multiply by attention map, store NCHW fp32
#pragma unroll
  for (int nt = 0; nt < 4; ++nt) {
    int n = wn * 64 + nt * 16 + l15;
    int r = n >> 6, w = n & 63;
    if (w < 56) {
      float av = amap[(b * 56 + h0 + r) * 56 + w];
#pragma unroll
      for (int mt = 0; mt < 4; ++mt) {
        int obase = mbase + wm * 64 + mt * 16 + lg * 4;
#pragma unroll
        for (int reg = 0; reg < 4; ++reg) {
          out[((size_t)(b * 256 + obase + reg) * 56 + h0 + r) * 56 + w] = acc[mt][nt][reg] * av;
        }
      }
    }
  }
}

extern "C" void kernel_launch(void* const* d_in, const int* in_sizes, int n_in,
                              void* d_out, int out_size, void* d_ws, size_t ws_size,
                              hipStream_t stream) {
  const float* x      = (const float*)d_in[0];
  const float* weight = (const float*)d_in[1];
  const float* A_w    = (const float*)d_in[2];
  const float* se_w1  = (const float*)d_in[3];
  const float* se_w2  = (const float*)d_in[4];
  float* out = (float*)d_out;

  char* ws = (char*)d_ws;
  // ws layout (bytes):
  // xp   : [8][58][58][256] bf16 = 13,778,944  (zero-padded -> memset)
  // wb   : [9][256][256]    bf16 =  1,179,648
  // w1b  : [9][16][256]     bf16 =     73,728
  // amap : [8][56][56]      f32  =    100,352
  u16* xp     = (u16*)ws;
  u16* wb     = (u16*)(ws + 13778944);
  u16* w1b    = (u16*)(ws + 14958592);
  float* amap = (float*)(ws + 15032320);
  // se1_pre [8][56][56][16] f32 = 1,605,632 B lives in d_out (scratch until k_main writes)
  float* se1_pre = (float*)d_out;

  hipMemsetAsync(xp, 0, 13778944, stream);
  hipMemsetAsync(se1_pre, 0, 1605632, stream);
  k_prep<<<dim3((589824 + 36864 + 255) / 256), dim3(256), 0, stream>>>(weight, A_w, se_w1, wb, w1b);
  k_transform<<<dim3(56, 8), dim3(256), 0, stream>>>(x, xp);
  k_se1<<<dim3(28, 8, 4), dim3(256), 0, stream>>>(xp, w1b, se1_pre);
  k_se2<<<dim3(392), dim3(64), 0, stream>>>(se1_pre, se_w2, amap);
  k_main<<<dim3(2, 28, 8), dim3(256), 0, stream>>>(xp, wb, amap, out);
}

// Round 3
// 154.321 us; speedup vs baseline: 1.3105x; 1.1190x over previous
//
#include <hip/hip_runtime.h>

// ALayer: out = conv3x3(x, weight*A_w) * sigmoid(conv3x3(relu(conv3x3(x,se_w1)), se_w2))
// B=8, C=256, H=W=56. bf16 MFMA implicit GEMM on NHWC-padded input.
// Round 3: k_main double-buffered with counted vmcnt(8) (loads in flight across
// barriers); k_se1 slab-reuse without atomics; k_se2 2-lane split.

typedef unsigned short u16;
typedef __bf16 bf16x8 __attribute__((ext_vector_type(8)));
typedef unsigned short us8 __attribute__((ext_vector_type(8)));
typedef unsigned short us4v __attribute__((ext_vector_type(4)));
typedef float f32x4 __attribute__((ext_vector_type(4)));
typedef float f4v __attribute__((ext_vector_type(4)));

#define HP 58   // padded H/W
#define HW 3136 // 56*56

__device__ __forceinline__ u16 f2bf(float f) {
  unsigned u = __float_as_uint(f);
  u = (u + 0x7fffu + ((u >> 16) & 1u)) >> 16;  // RNE, inputs finite
  return (u16)u;
}
__device__ __forceinline__ float bf2f(u16 v) {
  return __uint_as_float(((unsigned)v) << 16);
}

// async global->LDS, 16B per lane. LDS dest is wave-uniform base + lane*16.
__device__ __forceinline__ void gload16(const u16* g, u16* l) {
  __builtin_amdgcn_global_load_lds((const __attribute__((address_space(1))) void*)g,
                                   (__attribute__((address_space(3))) void*)l,
                                   16, 0, 0);
}

// ---------- prep: wb[tap][o][c] = bf16(weight[o][c][tap] * A_w[c][tap]);
//            w1b[tap][o16][c] = bf16(se_w1[o][c][tap])
__global__ void k_prep(const float* __restrict__ weight, const float* __restrict__ A_w,
                       const float* __restrict__ se_w1, u16* __restrict__ wb,
                       u16* __restrict__ w1b) {
  int idx = blockIdx.x * 256 + threadIdx.x;
  if (idx < 589824) {
    int tap = idx >> 16; int rem = idx & 65535; int o = rem >> 8; int c = rem & 255;
    wb[idx] = f2bf(weight[(o * 256 + c) * 9 + tap] * A_w[c * 9 + tap]);
  } else if (idx < 589824 + 36864) {
    int j = idx - 589824;
    int tap = j >> 12; int rem = j & 4095; int o = rem >> 8; int c = rem & 255;
    w1b[j] = f2bf(se_w1[(o * 256 + c) * 9 + tap]);
  }
}

// ---------- transform: x NCHW fp32 -> xp[b][58][58][256] bf16 (interior; border pre-zeroed)
__global__ __launch_bounds__(256) void k_transform(const float* __restrict__ x,
                                                   u16* __restrict__ xp) {
  __shared__ __align__(16) u16 trans[56 * 72];
  const int t = threadIdx.x;
  const int h = blockIdx.x;
  const int b = blockIdx.y;
  for (int cc = 0; cc < 4; ++cc) {
    const int c0 = cc * 64;
#pragma unroll
    for (int i = 0; i < 4; ++i) {
      int idx = t + 256 * i;
      if (idx < 896) {
        int ci = idx / 14, s = idx % 14;
        f4v v = *(const f4v*)(x + ((size_t)(b * 256 + c0 + ci)) * HW + h * 56 + s * 4);
#pragma unroll
        for (int j = 0; j < 4; ++j) trans[(s * 4 + j) * 72 + ci] = f2bf(v[j]);
      }
    }
    __syncthreads();
#pragma unroll
    for (int i = 0; i < 2; ++i) {
      int idx = t + 256 * i;
      if (idx < 448) {
        int w = idx >> 3, seg = idx & 7;
        us8 v = *(const us8*)&trans[w * 72 + seg * 8];
        *(us8*)(xp + ((size_t)((b * HP + h + 1) * HP + (w + 1))) * 256 + c0 + seg * 8) = v;
      }
    }
    __syncthreads();
  }
}

// ---------- SE conv1 + relu: M=16, N=128 (2 rows x 64), full K per block.
// Input slab staged once per cc and reused across all 9 taps.
__global__ __launch_bounds__(256) void k_se1(const u16* __restrict__ xp,
                                             const u16* __restrict__ w1b,
                                             u16* __restrict__ se1p) {
  __shared__ __align__(16) u16 Alds[144 * 8 * 8];       // 18432 B, swizzled [row][seg]
  __shared__ __align__(16) u16 slab[2080 * 8];          // 33280 B, [4 rows][64 cols][8 segs]+spill
  const int t = threadIdx.x;
  const int lane = t & 63;
  const int wv = t >> 6;
  const int l15 = lane & 15, lg = lane >> 4;
  const int h0 = blockIdx.x * 2;
  const int b = blockIdx.y;

  f32x4 acc[2];
  f32x4 z = {0.f, 0.f, 0.f, 0.f};
  acc[0] = z; acc[1] = z;

  for (int cc = 0; cc < 4; ++cc) {
    const int c0 = cc * 64;
    __syncthreads();
    // stage A: all 9 taps x 16 rows, swizzled store
    for (int idx = t; idx < 1152; idx += 256) {
      int row = idx >> 3, seg = idx & 7;
      us8 v = *(const us8*)(w1b + ((size_t)row * 256 + c0 + seg * 8));
      *(us8*)&Alds[(row * 8 + (seg ^ (row & 7))) * 8] = v;
    }
    // stage slab: 4 rows x 64 cols x 8 segs = 2048 chunks, pre-swizzled source
#pragma unroll
    for (int i = 0; i < 8; ++i) {
      int s_lin = wv * 512 + i * 64 + lane;
      int r = s_lin >> 9, col = (s_lin >> 3) & 63, seg = s_lin & 7;
      const u16* src = xp + ((size_t)((b * HP + h0 + r) * HP + col)) * 256 + c0 +
                       ((seg ^ (col & 7)) * 8);
      gload16(src, &slab[(wv * 512 + i * 64) * 8]);
    }
    __syncthreads();  // drains lgkm + vmcnt
    for (int dh = 0; dh < 3; ++dh) {
      for (int dw = 0; dw < 3; ++dw) {
        const int tap = dh * 3 + dw;
#pragma unroll
        for (int kk = 0; kk < 2; ++kk) {
          int arow = tap * 16 + l15;
          bf16x8 af = *(const bf16x8*)&Alds[(arow * 8 + ((kk * 4 + lg) ^ (arow & 7))) * 8];
#pragma unroll
          for (int nt = 0; nt < 2; ++nt) {
            int p = wv * 32 + nt * 16 + l15;
            int rr = (p >> 6) + dh, col = (p & 63) + dw;
            bf16x8 bfr = *(const bf16x8*)&slab[((rr * 64 + col) * 8 + ((kk * 4 + lg) ^ (col & 7))) * 8];
            acc[nt] = __builtin_amdgcn_mfma_f32_16x16x32_bf16(af, bfr, acc[nt], 0, 0, 0);
          }
        }
      }
    }
  }
  // epilogue: relu -> bf16, NHWC padded store
#pragma unroll
  for (int nt = 0; nt < 2; ++nt) {
    int p = wv * 32 + nt * 16 + l15;
    int r = p >> 6, w = p & 63;
    if (w < 56) {
      us4v pk;
#pragma unroll
      for (int reg = 0; reg < 4; ++reg) {
        float v = acc[nt][reg];
        v = v > 0.f ? v : 0.f;
        pk[reg] = f2bf(v);
      }
      *(us4v*)(se1p + ((size_t)((b * HP + h0 + r + 1) * HP + (w + 1))) * 16 + lg * 4) = pk;
    }
  }
}

// ---------- SE conv2 + sigmoid: 2 lanes per pixel, shuffle reduce
__global__ __launch_bounds__(256) void k_se2(const u16* __restrict__ se1p,
                                             const float* __restrict__ se_w2,
                                             float* __restrict__ amap) {
  __shared__ float w2s[144];
  const int t = threadIdx.x;
  for (int i = t; i < 144; i += 256) w2s[i] = se_w2[i];
  __syncthreads();
  int gid = blockIdx.x * 256 + t;
  int pix = gid >> 1, half = gid & 1;
  int b = pix / HW, p = pix % HW, h = p / 56, w = p % 56;
  float s = 0.f;
  for (int dh = 0; dh < 3; ++dh) {
#pragma unroll
    for (int dw = 0; dw < 3; ++dw) {
      const u16* src = se1p + ((size_t)((b * HP + h + dh) * HP + (w + dw))) * 16 + half * 8;
      us8 v = *(const us8*)src;
      int tap = dh * 3 + dw;
#pragma unroll
      for (int ci = 0; ci < 8; ++ci) s += bf2f(v[ci]) * w2s[(half * 8 + ci) * 9 + tap];
    }
  }
  s += __shfl_xor(s, 1);
  if (half == 0) amap[pix] = 1.f / (1.f + expf(-s));
}

// ---------- main conv: BM=128, BN=128 (2 rows x 64), 4 waves (2x2),
// double-buffered gload_lds with counted vmcnt(8) — loads in flight across barriers.
__global__ __launch_bounds__(256) void k_main(const u16* __restrict__ xp,
                                              const u16* __restrict__ wb,
                                              const float* __restrict__ amap,
                                              float* __restrict__ out) {
  __shared__ __align__(16) u16 Alds[2][8192];  // 2 x 16 KB
  __shared__ __align__(16) u16 Blds[2][8192];
  const int t = threadIdx.x;
  const int lane = t & 63;
  const int wid = t >> 6;
  const int wm = wid >> 1;          // 0..1 : 64 out-channels
  const int wn = wid & 1;           // 0..1 : 64 pixels
  const int l15 = lane & 15, lg = lane >> 4;
  const int lrow = lane >> 3, lseg = lane & 7;
  const int mbase = blockIdx.x * 128;
  const int h0 = blockIdx.y * 2;
  const int b = blockIdx.z;

  f32x4 acc[4][4];
  f32x4 z = {0.f, 0.f, 0.f, 0.f};
#pragma unroll
  for (int mt = 0; mt < 4; ++mt)
#pragma unroll
    for (int nt = 0; nt < 4; ++nt) acc[mt][nt] = z;

  auto stage = [&](int buf, int it) {
    const int tap = it >> 2, cc = it & 3;
    const int dh = tap / 3, dw = tap % 3;
    const int c0 = cc * 64;
#pragma unroll
    for (int i = 0; i < 4; ++i) {
      int li = wid * 4 + i;
      int row = li * 8 + lrow;  // 0..127 (A-row / B-pixel)
      const u16* srcA = wb + ((size_t)(tap * 256 + mbase + row)) * 256 + c0 +
                        ((lseg ^ (row & 7)) * 8);
      gload16(srcA, &Alds[buf][li * 512]);
      int r = row >> 6, w = row & 63;
      const u16* srcB = xp +
                        ((size_t)((b * HP + h0 + r + dh) * HP + (w + dw))) * 256 + c0 +
                        ((lseg ^ (row & 7)) * 8);
      gload16(srcB, &Blds[buf][li * 512]);
    }
  };

  stage(0, 0);
#pragma unroll 2
  for (int it = 0; it < 36; ++it) {
    const int cur = it & 1;
    if (it < 35) {
      stage(cur ^ 1, it + 1);
      asm volatile("s_waitcnt vmcnt(8)" ::: "memory");  // current tile's loads landed
    } else {
      asm volatile("s_waitcnt vmcnt(0)" ::: "memory");
    }
    __builtin_amdgcn_s_barrier();
    __builtin_amdgcn_sched_barrier(0);  // pin: no ds_read hoists above the barrier
#pragma unroll
    for (int kk = 0; kk < 2; ++kk) {
      bf16x8 af[4], bfr[4];
#pragma unroll
      for (int mt = 0; mt < 4; ++mt) {
        int row = wm * 64 + mt * 16 + l15;
        af[mt] = *(const bf16x8*)&Alds[cur][row * 64 + (((kk * 4 + lg) ^ (row & 7)) * 8)];
      }
#pragma unroll
      for (int nt = 0; nt < 4; ++nt) {
        int p = wn * 64 + nt * 16 + l15;
        bfr[nt] = *(const bf16x8*)&Blds[cur][p * 64 + (((kk * 4 + lg) ^ (p & 7)) * 8)];
      }
#pragma unroll
      for (int mt = 0; mt < 4; ++mt)
#pragma unroll
        for (int nt = 0; nt < 4; ++nt)
          acc[mt][nt] = __builtin_amdgcn_mfma_f32_16x16x32_bf16(af[mt], bfr[nt], acc[mt][nt], 0, 0, 0);
    }
    __builtin_amdgcn_sched_barrier(0);  // reads done before end barrier
    __builtin_amdgcn_s_barrier();       // safe to overwrite buf cur next iteration
  }
  // epilogue: multiply by attention map, store NCHW fp32
#pragma unroll
  for (int nt = 0; nt < 4; ++nt) {
    int n = wn * 64 + nt * 16 + l15;
    int r = n >> 6, w = n & 63;
    if (w < 56) {
      float av = amap[(b * 56 + h0 + r) * 56 + w];
#pragma unroll
      for (int mt = 0; mt < 4; ++mt) {
        int obase = mbase + wm * 64 + mt * 16 + lg * 4;
#pragma unroll
        for (int reg = 0; reg < 4; ++reg) {
          out[((size_t)(b * 256 + obase + reg) * 56 + h0 + r) * 56 + w] = acc[mt][nt][reg] * av;
        }
      }
    }
  }
}

extern "C" void kernel_launch(void* const* d_in, const int* in_sizes, int n_in,
                              void* d_out, int out_size, void* d_ws, size_t ws_size,
                              hipStream_t stream) {
  const float* x      = (const float*)d_in[0];
  const float* weight = (const float*)d_in[1];
  const float* A_w    = (const float*)d_in[2];
  const float* se_w1  = (const float*)d_in[3];
  const float* se_w2  = (const float*)d_in[4];
  float* out = (float*)d_out;

  char* ws = (char*)d_ws;
  // ws layout (bytes):
  // xp   : [8][58][58][256] bf16 = 13,778,944  (zero-padded)
  // se1p : [8][58][58][16]  bf16 =    861,184  (zero-padded)  -> one memset covers both
  // wb   : [9][256][256]    bf16 =  1,179,648
  // w1b  : [9][16][256]     bf16 =     73,728
  // amap : [8][56][56]      f32  =    100,352
  u16* xp     = (u16*)ws;
  u16* se1p   = (u16*)(ws + 13778944);
  u16* wb     = (u16*)(ws + 14640128);
  u16* w1b    = (u16*)(ws + 15819776);
  float* amap = (float*)(ws + 15893504);

  hipMemsetAsync(ws, 0, 14640128, stream);  // zero xp + se1p padding
  k_prep<<<dim3((589824 + 36864 + 255) / 256), dim3(256), 0, stream>>>(weight, A_w, se_w1, wb, w1b);
  k_transform<<<dim3(56, 8), dim3(256), 0, stream>>>(x, xp);
  k_se1<<<dim3(28, 8), dim3(256), 0, stream>>>(xp, w1b, se1p);
  k_se2<<<dim3(196), dim3(256), 0, stream>>>(se1p, se_w2, amap);
  k_main<<<dim3(2, 28, 8), dim3(256), 0, stream>>>(xp, wb, amap, out);
}